// Round 14
// baseline (459.807 us; speedup 1.0000x reference)
//
#include <hip/hip_runtime.h>

// out[b,s,o] = sum_i x[b,s,i] * qw[o,i],  qw = ternary(W, 0.3)
// ~0.27% nonzeros => sparse signed gather-add.
// R9: predicated 12-slot unroll -> LDS-issue-bound (99us).
// R10: sort+uniform-exit -> 83us, occupancy 58%, ~160us prep/launch overhead.
// R11: fused prep + 1 tile/block + nontemporal stores.
// R12: fix - __builtin_nontemporal_store needs native clang vector, not
//      HIP_vector_type; use ext_vector_type(4) float.

#define TH    0.3f
#define NSLOT 16
#define ROWS  16      // 32 KB LDS tile
#define KDIM  512
#define NDIM  512

typedef float floatx4 __attribute__((ext_vector_type(4)));

// ---------------- Kernel 1: fused table build + sort (1 block, 512 thr) ------
__global__ __launch_bounds__(512) void prep(const float* __restrict__ w,
                                            int* __restrict__ perm,
                                            int* __restrict__ scnt,
                                            int* __restrict__ stbl,
                                            int* __restrict__ tbl) {
    const int t    = threadIdx.x;
    const int lane = t & 63;
    const int wv   = t >> 6;                 // wave 0..7
    __shared__ int counts[NDIM];
    __shared__ int hist[NSLOT + 2];

    // phase 1: wave wv scans W rows [wv*64, wv*64+64), coalesced + ballot-compact
    for (int r = wv * 64; r < wv * 64 + 64; ++r) {
        const float* row = w + (size_t)r * KDIM;
        int cnt = 0;
        for (int it = 0; it < 8; ++it) {
            const int i = it * 64 + lane;
            const float v = row[i];
            const bool m = (v > TH) || (v < -TH);       // strict, matches ref
            const unsigned long long mask = __ballot(m);
            if (m) {
                int pos = cnt + __popcll(mask & ((1ull << lane) - 1ull));
                if (pos < NSLOT) tbl[r * NSLOT + pos] = (i << 1) | (v < 0.0f ? 1 : 0);
            }
            cnt += __popcll(mask);
        }
        if (lane == 0) counts[r] = cnt;
        if (lane >= cnt && lane < NSLOT) tbl[r * NSLOT + lane] = 0;  // zero-pad
    }
    if (t < NSLOT + 2) hist[t] = 0;
    __syncthreads();

    // phase 2: counting sort by cnt, descending
    const int cnt = counts[t];
    const int key = cnt < NSLOT + 1 ? cnt : NSLOT + 1;
    atomicAdd(&hist[key], 1);
    __syncthreads();
    if (t == 0) {
        int run = 0;
        for (int k = NSLOT + 1; k >= 0; --k) { int h = hist[k]; hist[k] = run; run += h; }
    }
    __syncthreads();
    const int pos = atomicAdd(&hist[key], 1);
    perm[pos] = t;
    scnt[pos] = cnt;
    for (int k = 0; k < NSLOT; ++k) stbl[pos * NSLOT + k] = tbl[t * NSLOT + k];
}

// ---------------- Kernel 2: streaming sparse gather-add (1 tile per block) ---
__global__ __launch_bounds__(512, 8) void ternary_mm(
        const float* __restrict__ x, const float* __restrict__ w,
        const int* __restrict__ perm, const int* __restrict__ scnt,
        const int* __restrict__ stbl, float* __restrict__ out) {
    __shared__ float xs[ROWS * KDIM];                 // 32 KB, also out-bounce

    const int t  = threadIdx.x;
    const int c  = perm[t];                           // my output column
    const int ct = scnt[t];
    int e[NSLOT];
#pragma unroll
    for (int k = 0; k < NSLOT; ++k) e[k] = stbl[t * NSLOT + k];

    const int fast = (ct <= NSLOT) ? ct : 0;
    int wm = fast;                                    // wave-max fast count
#pragma unroll
    for (int off = 32; off; off >>= 1) { int o2 = __shfl_xor(wm, off); wm = wm > o2 ? wm : o2; }
    wm = __builtin_amdgcn_readfirstlane(wm);          // scalar loop bound

    const size_t base = (size_t)blockIdx.x * (ROWS * KDIM);

    {   // stage 32 KB tile, coalesced
        const floatx4* src = (const floatx4*)(x + base);
        floatx4 a0 = src[0 * 512 + t], a1 = src[1 * 512 + t];
        floatx4 a2 = src[2 * 512 + t], a3 = src[3 * 512 + t];
        floatx4* dst = (floatx4*)xs;
        dst[0 * 512 + t] = a0; dst[1 * 512 + t] = a1;
        dst[2 * 512 + t] = a2; dst[3 * 512 + t] = a3;
    }
    __syncthreads();

    float acc[ROWS];
#pragma unroll
    for (int r = 0; r < ROWS; ++r) acc[r] = 0.0f;

    if (ct <= NSLOT) {
#pragma unroll
        for (int k = 0; k < NSLOT; ++k) {
            if (k >= wm) break;                       // uniform: skips issue
            if (k < fast) {                           // per-lane predicate
                const int idx = e[k] >> 1;
                const int sm  = (e[k] & 1) << 31;
#pragma unroll
                for (int r = 0; r < ROWS; ++r) {
                    float v = xs[r * KDIM + idx];
                    acc[r] += __int_as_float(__float_as_int(v) ^ sm);
                }
            }
        }
    } else {
        // parachute: rescan weight row from global (P ~ 1e-15)
        const float* wrow = w + (size_t)c * KDIM;
        for (int i = 0; i < KDIM; ++i) {
            const float wv = wrow[i];
            if (wv > TH || wv < -TH) {
                const int sm = (wv < 0.0f) ? (1 << 31) : 0;
#pragma unroll
                for (int r = 0; r < ROWS; ++r) {
                    float v = xs[r * KDIM + i];
                    acc[r] += __int_as_float(__float_as_int(v) ^ sm);
                }
            }
        }
    }

    __syncthreads();                                  // all gather reads done
#pragma unroll
    for (int r = 0; r < ROWS; ++r)                    // bounce: scatter by column
        xs[r * KDIM + c] = acc[r];
    __syncthreads();                                  // bounce visible

    {   // coalesced nontemporal stores (don't evict x from L3)
        floatx4* dst = (floatx4*)(out + base);
        const floatx4* s4 = (const floatx4*)xs;
        __builtin_nontemporal_store(s4[0 * 512 + t], &dst[0 * 512 + t]);
        __builtin_nontemporal_store(s4[1 * 512 + t], &dst[1 * 512 + t]);
        __builtin_nontemporal_store(s4[2 * 512 + t], &dst[2 * 512 + t]);
        __builtin_nontemporal_store(s4[3 * 512 + t], &dst[3 * 512 + t]);
    }
}

extern "C" void kernel_launch(void* const* d_in, const int* in_sizes, int n_in,
                              void* d_out, int out_size, void* d_ws, size_t ws_size,
                              hipStream_t stream) {
    const float* x = (const float*)d_in[0];   // [16,4096,512] f32
    const float* w = (const float*)d_in[1];   // [512,512] f32
    float* out = (float*)d_out;               // [16,4096,512] f32

    int* perm = (int*)d_ws;                       // 512
    int* scnt = perm + NDIM;                      // 512
    int* stbl = scnt + NDIM;                      // 512*16
    int* tbl  = stbl + NDIM * NSLOT;              // 512*16   (~68 KB total)

    const int nrows  = in_sizes[0] / KDIM;        // 65536
    const int ntiles = nrows / ROWS;              // 4096

    prep<<<1, 512, 0, stream>>>(w, perm, scnt, stbl, tbl);
    ternary_mm<<<ntiles, 512, 0, stream>>>(x, w, perm, scnt, stbl, out);
}

// Round 15
// 244.354 us; speedup vs baseline: 1.8817x; 1.8817x over previous
//
#include <hip/hip_runtime.h>

// out[b,s,o] = sum_i x[b,s,i] * qw[o,i],  qw = ternary(W, 0.3)
// ~0.27% nonzeros => sparse signed gather-add.
// R9:  predicated 12-slot unroll -> LDS-issue-bound (99us).
// R10: sort+uniform-exit -> 83us, occupancy 58% (grid-stride serialization).
// R14: 1-block fused prep = latency-bound 228us regression (occupancy 0.09%).
// R15: parallel prep (512-block ballot build + tiny sort) + R11 ternary_mm
//      (1 tile/block grid=4096, nontemporal stores).

#define TH    0.3f
#define NSLOT 16
#define ROWS  16      // 32 KB LDS tile
#define KDIM  512
#define NDIM  512

typedef float floatx4 __attribute__((ext_vector_type(4)));

// ---------------- Kernel 1: per-row entry lists (512 blocks x 64 thr) --------
__global__ __launch_bounds__(64) void build_tbl(const float* __restrict__ w,
                                                int* __restrict__ counts,
                                                int* __restrict__ tbl) {
    const int o    = blockIdx.x;
    const int lane = threadIdx.x;
    const float* row = w + (size_t)o * KDIM;
    int cnt = 0;
#pragma unroll
    for (int it = 0; it < 8; ++it) {
        const int i = it * 64 + lane;
        const float v = row[i];
        const bool m = (v > TH) || (v < -TH);            // strict, matches ref
        const unsigned long long mask = __ballot(m);
        if (m) {
            int pos = cnt + __popcll(mask & ((1ull << lane) - 1ull));
            if (pos < NSLOT) tbl[o * NSLOT + pos] = (i << 1) | (v < 0.0f ? 1 : 0);
        }
        cnt += __popcll(mask);
    }
    if (lane == 0) counts[o] = cnt;
    if (lane >= cnt && lane < NSLOT) tbl[o * NSLOT + lane] = 0;   // zero-pad
}

// ---------------- Kernel 2: counting-sort columns by cnt, descending ---------
__global__ __launch_bounds__(512) void sort_cols(const int* __restrict__ counts,
                                                 const int* __restrict__ tbl,
                                                 int* __restrict__ perm,
                                                 int* __restrict__ scnt,
                                                 int* __restrict__ stbl) {
    const int t = threadIdx.x;
    const int cnt = counts[t];
    const int key = cnt < (NSLOT + 1) ? cnt : (NSLOT + 1);
    __shared__ int base[NSLOT + 2];
    if (t < NSLOT + 2) base[t] = 0;
    __syncthreads();
    atomicAdd(&base[key], 1);
    __syncthreads();
    if (t == 0) {                        // descending exclusive scan
        int run = 0;
        for (int k = NSLOT + 1; k >= 0; --k) { int h = base[k]; base[k] = run; run += h; }
    }
    __syncthreads();
    const int pos = atomicAdd(&base[key], 1);
    perm[pos] = t;
    scnt[pos] = cnt;
#pragma unroll
    for (int k = 0; k < NSLOT; ++k) stbl[pos * NSLOT + k] = tbl[t * NSLOT + k];
}

// ---------------- Kernel 3: streaming sparse gather-add (1 tile/block) -------
__global__ __launch_bounds__(512, 8) void ternary_mm(
        const float* __restrict__ x, const float* __restrict__ w,
        const int* __restrict__ perm, const int* __restrict__ scnt,
        const int* __restrict__ stbl, float* __restrict__ out) {
    __shared__ float xs[ROWS * KDIM];                 // 32 KB, also out-bounce

    const int t  = threadIdx.x;
    const int c  = perm[t];                           // my output column
    const int ct = scnt[t];
    int e[NSLOT];
#pragma unroll
    for (int k = 0; k < NSLOT; ++k) e[k] = stbl[t * NSLOT + k];

    const int fast = (ct <= NSLOT) ? ct : 0;
    int wm = fast;                                    // wave-max fast count
#pragma unroll
    for (int off = 32; off; off >>= 1) { int o2 = __shfl_xor(wm, off); wm = wm > o2 ? wm : o2; }
    wm = __builtin_amdgcn_readfirstlane(wm);          // scalar loop bound

    const size_t base = (size_t)blockIdx.x * (ROWS * KDIM);

    {   // stage 32 KB tile, coalesced
        const floatx4* src = (const floatx4*)(x + base);
        floatx4 a0 = src[0 * 512 + t], a1 = src[1 * 512 + t];
        floatx4 a2 = src[2 * 512 + t], a3 = src[3 * 512 + t];
        floatx4* dst = (floatx4*)xs;
        dst[0 * 512 + t] = a0; dst[1 * 512 + t] = a1;
        dst[2 * 512 + t] = a2; dst[3 * 512 + t] = a3;
    }
    __syncthreads();

    float acc[ROWS];
#pragma unroll
    for (int r = 0; r < ROWS; ++r) acc[r] = 0.0f;

    if (ct <= NSLOT) {
#pragma unroll
        for (int k = 0; k < NSLOT; ++k) {
            if (k >= wm) break;                       // uniform: skips issue
            if (k < fast) {                           // per-lane predicate
                const int idx = e[k] >> 1;
                const int sm  = (e[k] & 1) << 31;
#pragma unroll
                for (int r = 0; r < ROWS; ++r) {
                    float v = xs[r * KDIM + idx];
                    acc[r] += __int_as_float(__float_as_int(v) ^ sm);
                }
            }
        }
    } else {
        // parachute: rescan weight row from global (P ~ 1e-15)
        const float* wrow = w + (size_t)c * KDIM;
        for (int i = 0; i < KDIM; ++i) {
            const float wv = wrow[i];
            if (wv > TH || wv < -TH) {
                const int sm = (wv < 0.0f) ? (1 << 31) : 0;
#pragma unroll
                for (int r = 0; r < ROWS; ++r) {
                    float v = xs[r * KDIM + i];
                    acc[r] += __int_as_float(__float_as_int(v) ^ sm);
                }
            }
        }
    }

    __syncthreads();                                  // all gather reads done
#pragma unroll
    for (int r = 0; r < ROWS; ++r)                    // bounce: scatter by column
        xs[r * KDIM + c] = acc[r];
    __syncthreads();                                  // bounce visible

    {   // coalesced nontemporal stores (don't evict x from L3)
        floatx4* dst = (floatx4*)(out + base);
        const floatx4* s4 = (const floatx4*)xs;
        __builtin_nontemporal_store(s4[0 * 512 + t], &dst[0 * 512 + t]);
        __builtin_nontemporal_store(s4[1 * 512 + t], &dst[1 * 512 + t]);
        __builtin_nontemporal_store(s4[2 * 512 + t], &dst[2 * 512 + t]);
        __builtin_nontemporal_store(s4[3 * 512 + t], &dst[3 * 512 + t]);
    }
}

extern "C" void kernel_launch(void* const* d_in, const int* in_sizes, int n_in,
                              void* d_out, int out_size, void* d_ws, size_t ws_size,
                              hipStream_t stream) {
    const float* x = (const float*)d_in[0];   // [16,4096,512] f32
    const float* w = (const float*)d_in[1];   // [512,512] f32
    float* out = (float*)d_out;               // [16,4096,512] f32

    int* counts = (int*)d_ws;                     // 512
    int* tbl    = counts + NDIM;                  // 512*16
    int* perm   = tbl + NDIM * NSLOT;             // 512
    int* scnt   = perm + NDIM;                    // 512
    int* stbl   = scnt + NDIM;                    // 512*16  (~72 KB total)

    const int nrows  = in_sizes[0] / KDIM;        // 65536
    const int ntiles = nrows / ROWS;              // 4096

    build_tbl<<<NDIM, 64, 0, stream>>>(w, counts, tbl);
    sort_cols<<<1, 512, 0, stream>>>(counts, tbl, perm, scnt, stbl);
    ternary_mm<<<ntiles, 512, 0, stream>>>(x, w, perm, scnt, stbl, out);
}